// Round 4
// baseline (732.698 us; speedup 1.0000x reference)
//
#include <hip/hip_runtime.h>
#include <math.h>

constexpr int      kLevels = 16;
constexpr unsigned kT      = 1u << 19;
constexpr int      kHidden = 64;
constexpr int      kInDim  = 32;
constexpr int      kOutDim = 16;

struct LevelParams {
    float    scale[kLevels];
    unsigned res[kLevels];
    unsigned dense[kLevels];
};

typedef __attribute__((ext_vector_type(8))) short bf16x8;
typedef __attribute__((ext_vector_type(4))) float f32x4;
typedef __attribute__((ext_vector_type(2))) unsigned uint2v;

// ---- manual bf16 helpers ----
__device__ inline float bf2f(unsigned short b) {
    unsigned u = ((unsigned)b) << 16;
    return __builtin_bit_cast(float, u);
}
__device__ inline unsigned short f2bf(float f) {
    unsigned u = __builtin_bit_cast(unsigned, f);
    unsigned r = (u + 0x7fffu + ((u >> 16) & 1u)) >> 16;   // RTN-even
    return (unsigned short)r;
}
__device__ inline unsigned pack2bf(float a, float b) {
    return (unsigned)f2bf(a) | ((unsigned)f2bf(b) << 16);
}

// ---- kernel T: f32 table -> packed bf16 table in ws ----
__global__ __launch_bounds__(256) void convert_table(
        const float* __restrict__ t, unsigned* __restrict__ o, int n4)
{
    int i = blockIdx.x * blockDim.x + threadIdx.x;
    if (i >= n4) return;
    float4 v = ((const float4*)t)[i];
    ((uint2*)o)[i] = make_uint2(pack2bf(v.x, v.y), pack2bf(v.z, v.w));
}

// ---- R7: fully fused encode + MFMA MLP.
// History: encode stream is at a fixed divergent-request floor ~270us
// (R5: cache-tier irrelevant — L2 pinning halved FETCH, time -3%;
// R6: occupancy 88->53% at same throughput — saturates ~16 waves/CU;
// MLP-widening null). The split mlp_mfma kernel added ~140us of
// latency-bound tail on 20us of traffic. Fuse: each wave encodes its
// 16-point tile directly into the MFMA A-fragment (lane (quad,l16)
// owns levels 4*quad..4*quad+3 of point P+l16 — exactly the layout
// loadFrag used to read from the enc buffer) and runs the MLP in the
// gather-stall shadow. Kills 128MB of enc roundtrip + the tail.
// Keep: NO nt on table gathers (R4: defeats L2, 2x regression);
// pack2bf rounding identical to the verified split path.
__global__ __launch_bounds__(256) void fused_enc_mlp(
        const float* __restrict__ x,
        const unsigned* __restrict__ tblAll,   // [16][kT] packed bf16x2
        const float* __restrict__ W0,
        const float* __restrict__ b0,
        const float* __restrict__ W1,
        const float* __restrict__ b1,
        float* __restrict__ out, int N, int nTiles, LevelParams lp)
{
    constexpr int kHStride = 72;
    __shared__ short lds_h[4][16 * kHStride];

    const int wave = threadIdx.x >> 6;
    const int lane = threadIdx.x & 63;
    const int quad = lane >> 4;
    const int l16  = lane & 15;

    union Frag { bf16x8 v; short s[8]; unsigned u[4]; };

    // ---- weight fragments (identical to mlp_mfma) ----
    Frag w0f[4];
    #pragma unroll
    for (int hb = 0; hb < 4; ++hb) {
        #pragma unroll
        for (int j = 0; j < 8; ++j) {
            const int k = quad * 8 + j;
            const int n = hb * 16 + l16;
            w0f[hb].s[j] = (short)f2bf(W0[n * kInDim + k]);
        }
    }
    Frag w1f[2];
    #pragma unroll
    for (int kb = 0; kb < 2; ++kb) {
        #pragma unroll
        for (int j = 0; j < 8; ++j) {
            const int k = kb * 32 + quad * 8 + j;
            const int n = l16;
            w1f[kb].s[j] = (short)f2bf(W1[n * kHidden + k]);
        }
    }
    float b0v[4];
    #pragma unroll
    for (int hb = 0; hb < 4; ++hb) b0v[hb] = b0[hb * 16 + l16];
    const float b1v = b1[l16];

    // ---- per-lane level params for myl = quad*4 + j2 (constant-index
    // select — avoids scratch from runtime indexing of kernel args) ----
    float    lscale[4];
    unsigned lres[4];
    unsigned ldense[4];
    #pragma unroll
    for (int j2 = 0; j2 < 4; ++j2) {
        const int myl = quad * 4 + j2;
        float sc = lp.scale[0]; unsigned rs = lp.res[0]; unsigned dn = lp.dense[0];
        #pragma unroll
        for (int ll = 1; ll < kLevels; ++ll) {
            if (myl == ll) { sc = lp.scale[ll]; rs = lp.res[ll]; dn = lp.dense[ll]; }
        }
        lscale[j2] = sc; lres[j2] = rs; ldense[j2] = dn;
    }

    short* hrow = lds_h[wave];
    const int waveGlobal = blockIdx.x * 4 + wave;
    const int nWaves     = gridDim.x * 4;

    for (int t = waveGlobal; t < nTiles; t += nWaves) {
        const int P = t * 16;
        int p = P + l16;
        if (p >= N) p = N - 1;

        const float x0 = fminf(fmaxf((x[3 * p + 0] + 1.0f) * 0.5f, 0.0f), 1.0f);
        const float y0 = fminf(fmaxf((x[3 * p + 1] + 1.0f) * 0.5f, 0.0f), 1.0f);
        const float z0 = fminf(fmaxf((x[3 * p + 2] + 1.0f) * 0.5f, 0.0f), 1.0f);

        // ---- gather phase: 4 levels/lane, addresses + loads ----
        unsigned v0[4][4], v1[4][4];
        float    ffx[4], ffy[4], ffz[4];

        #pragma unroll
        for (int j2 = 0; j2 < 4; ++j2) {
            const unsigned* tbl = tblAll + (size_t)(quad * 4 + j2) * kT;
            const float scale = lscale[j2];
            const unsigned res = lres[j2];
            const bool dense = (ldense[j2] != 0);

            const float posx = x0 * scale + 0.5f;
            const float posy = y0 * scale + 0.5f;
            const float posz = z0 * scale + 0.5f;
            const float fgx = floorf(posx), fgy = floorf(posy), fgz = floorf(posz);
            const float fx = posx - fgx, fy = posy - fgy, fz = posz - fgz;
            const unsigned ix = (unsigned)fgx, iy = (unsigned)fgy, iz = (unsigned)fgz;
            ffx[j2] = fx; ffy[j2] = fy; ffz[j2] = fz;

            #pragma unroll
            for (int c2 = 0; c2 < 4; ++c2) {
                const unsigned cy = iy + (c2 & 1);
                const unsigned cz = iz + (c2 >> 1);

                if (dense) {
                    const unsigned base = cy * res + cz * res * res;
                    const unsigned idx0 = (ix + base) & (kT - 1u);
                    if ((idx0 & 1u) == 0u) {
                        const uint2v pr = *(const uint2v*)(tbl + idx0);
                        v0[j2][c2] = pr.x; v1[j2][c2] = pr.y;
                    } else {
                        v0[j2][c2] = tbl[idx0];
                        v1[j2][c2] = tbl[idx0 + 1u];
                    }
                } else {
                    const unsigned base = (cy * 2654435761u) ^ (cz * 805459861u);
                    const unsigned idx0 = (ix ^ base) & (kT - 1u);
                    if ((ix & 1u) == 0u) {
                        const unsigned b = idx0 & ~1u;
                        const uint2v pr = *(const uint2v*)(tbl + b);
                        const bool sw = (idx0 & 1u) != 0u;
                        v0[j2][c2] = sw ? pr.y : pr.x;
                        v1[j2][c2] = sw ? pr.x : pr.y;
                    } else {
                        const unsigned idx1 = ((ix + 1u) ^ base) & (kT - 1u);
                        v0[j2][c2] = tbl[idx0];
                        v1[j2][c2] = tbl[idx1];
                    }
                }
            }
        }

        // ---- interpolate -> A fragment (same rounding as enc path) ----
        Frag af;
        #pragma unroll
        for (int j2 = 0; j2 < 4; ++j2) {
            const float fx = ffx[j2], fy = ffy[j2], fz = ffz[j2];
            const float gx = 1.0f - fx, gy = 1.0f - fy, gz = 1.0f - fz;
            float a0 = 0.0f, a1 = 0.0f;
            #pragma unroll
            for (int c2 = 0; c2 < 4; ++c2) {
                const float wyz = ((c2 & 1) ? fy : gy) * ((c2 >> 1) ? fz : gz);
                const float w0 = gx * wyz;
                const float w1 = fx * wyz;
                a0 = fmaf(bf2f((unsigned short)(v0[j2][c2] & 0xffffu)), w0, a0);
                a1 = fmaf(bf2f((unsigned short)(v0[j2][c2] >> 16)),     w0, a1);
                a0 = fmaf(bf2f((unsigned short)(v1[j2][c2] & 0xffffu)), w1, a0);
                a1 = fmaf(bf2f((unsigned short)(v1[j2][c2] >> 16)),     w1, a1);
            }
            af.u[j2] = pack2bf(a0, a1);
        }

        // ---- MLP (identical to mlp_mfma) ----
        f32x4 acc[4];
        #pragma unroll
        for (int hb = 0; hb < 4; ++hb) {
            acc[hb] = f32x4{b0v[hb], b0v[hb], b0v[hb], b0v[hb]};
            acc[hb] = __builtin_amdgcn_mfma_f32_16x16x32_bf16(
                          af.v, w0f[hb].v, acc[hb], 0, 0, 0);
        }

        #pragma unroll
        for (int hb = 0; hb < 4; ++hb) {
            #pragma unroll
            for (int r = 0; r < 4; ++r) {
                const float a = acc[hb][r];
                const float z = 100.0f * a;
                const float h = (z > 20.0f) ? a
                              : (__logf(1.0f + __expf(z)) * 0.01f);
                const int row = quad * 4 + r;
                const int col = hb * 16 + l16;
                hrow[row * kHStride + col] = (short)f2bf(h);
            }
        }
        bf16x8 h0 = *(const bf16x8*)&hrow[l16 * kHStride + quad * 8];
        bf16x8 h1 = *(const bf16x8*)&hrow[l16 * kHStride + 32 + quad * 8];

        f32x4 acc2 = f32x4{b1v, b1v, b1v, b1v};
        acc2 = __builtin_amdgcn_mfma_f32_16x16x32_bf16(h0, w1f[0].v, acc2, 0, 0, 0);
        acc2 = __builtin_amdgcn_mfma_f32_16x16x32_bf16(h1, w1f[1].v, acc2, 0, 0, 0);

        #pragma unroll
        for (int r = 0; r < 4; ++r) {
            const int pp = P + quad * 4 + r;
            if (pp < N) {
                if (l16 == 0) out[pp] = acc2[r];
                else out[(size_t)N + (size_t)pp * 15u + (l16 - 1)] = acc2[r];
            }
        }
    }
}

// ---- fallback: fused scalar kernel (used only if ws too small) ----
__global__ __launch_bounds__(256) void sdf_fused(
        const float* __restrict__ x, const float* __restrict__ table,
        const float* __restrict__ W0, const float* __restrict__ b0,
        const float* __restrict__ W1, const float* __restrict__ b1,
        float* __restrict__ out, int N, LevelParams lp)
{
    const int gid = blockIdx.x * blockDim.x + threadIdx.x;
    if (gid >= N) return;
    const float x0 = fminf(fmaxf((x[3 * gid + 0] + 1.0f) * 0.5f, 0.0f), 1.0f);
    const float y0 = fminf(fmaxf((x[3 * gid + 1] + 1.0f) * 0.5f, 0.0f), 1.0f);
    const float z0 = fminf(fmaxf((x[3 * gid + 2] + 1.0f) * 0.5f, 0.0f), 1.0f);
    float enc[kInDim];
    #pragma unroll
    for (int l = 0; l < kLevels; ++l) {
        const float scale = lp.scale[l];
        const unsigned res = lp.res[l];
        const bool dense = (lp.dense[l] != 0);
        const float posx = x0 * scale + 0.5f, posy = y0 * scale + 0.5f, posz = z0 * scale + 0.5f;
        const float fgx = floorf(posx), fgy = floorf(posy), fgz = floorf(posz);
        const float fx = posx - fgx, fy = posy - fgy, fz = posz - fgz;
        const float gx = 1.0f - fx, gy = 1.0f - fy, gz = 1.0f - fz;
        const unsigned ix = (unsigned)fgx, iy = (unsigned)fgy, iz = (unsigned)fgz;
        const float* tbl = table + (size_t)l * kT * 2u;
        float a0 = 0.0f, a1 = 0.0f;
        #pragma unroll
        for (int c = 0; c < 8; ++c) {
            const unsigned cx = ix + (c & 1), cy = iy + ((c >> 1) & 1), cz = iz + ((c >> 2) & 1);
            unsigned idx = dense ? (cx + cy * res + cz * res * res)
                                 : (cx ^ (cy * 2654435761u) ^ (cz * 805459861u));
            idx &= (kT - 1u);
            const float2 tv = *(const float2*)(tbl + 2u * idx);
            const float w = ((c & 1) ? fx : gx) * (((c >> 1) & 1) ? fy : gy) * (((c >> 2) & 1) ? fz : gz);
            a0 = fmaf(tv.x, w, a0); a1 = fmaf(tv.y, w, a1);
        }
        enc[2 * l] = a0; enc[2 * l + 1] = a1;
    }
    float acc[kOutDim];
    #pragma unroll
    for (int k = 0; k < kOutDim; ++k) acc[k] = b1[k];
    #pragma unroll 2
    for (int j = 0; j < kHidden; ++j) {
        float a = b0[j];
        #pragma unroll
        for (int i = 0; i < kInDim; ++i) a = fmaf(enc[i], W0[j * kInDim + i], a);
        const float z = 100.0f * a;
        const float h = (z > 20.0f) ? a : (__logf(1.0f + __expf(z)) * 0.01f);
        #pragma unroll
        for (int k = 0; k < kOutDim; ++k) acc[k] = fmaf(h, W1[k * kHidden + j], acc[k]);
    }
    out[gid] = acc[0];
    #pragma unroll
    for (int k = 0; k < 15; ++k) out[(size_t)N + (size_t)gid * 15u + k] = acc[k + 1];
}

extern "C" void kernel_launch(void* const* d_in, const int* in_sizes, int n_in,
                              void* d_out, int out_size, void* d_ws, size_t ws_size,
                              hipStream_t stream) {
    const float* x     = (const float*)d_in[0];
    const float* table = (const float*)d_in[1];
    const float* W0    = (const float*)d_in[2];
    const float* b0    = (const float*)d_in[3];
    const float* W1    = (const float*)d_in[4];
    const float* b1    = (const float*)d_in[5];
    float* out = (float*)d_out;
    const int N = in_sizes[0] / 3;

    LevelParams lp;
    const double s = exp2(7.0 / 15.0);
    for (int l = 0; l < kLevels; ++l) {
        const double sc = 16.0 * pow(s, (double)l) - 1.0;
        lp.scale[l] = (float)sc;
        const unsigned res = (unsigned)ceil(sc) + 1u;
        lp.res[l] = res;
        lp.dense[l] =
            ((unsigned long long)res * res * res <= (unsigned long long)kT) ? 1u : 0u;
    }

    const size_t tbl_bytes = (size_t)kLevels * kT * 4u;              // 32 MB packed bf16x2

    if (ws_size >= tbl_bytes) {
        unsigned* tbl_bf = (unsigned*)d_ws;

        const int n4 = (int)(kLevels * kT * 2u / 4u);
        hipLaunchKernelGGL(convert_table, dim3((n4 + 255) / 256), dim3(256), 0, stream,
                           table, tbl_bf, n4);

        const int nTiles = (N + 15) / 16;
        hipLaunchKernelGGL(fused_enc_mlp, dim3(2048), dim3(256), 0, stream,
                           x, tbl_bf, W0, b0, W1, b1, out, N, nTiles, lp);
    } else {
        hipLaunchKernelGGL(sdf_fused, dim3((N + 255) / 256), dim3(256), 0, stream,
                           x, table, W0, b0, W1, b1, out, N, lp);
    }
}

// Round 5
// 620.659 us; speedup vs baseline: 1.1805x; 1.1805x over previous
//
#include <hip/hip_runtime.h>
#include <math.h>

constexpr int      kLevels = 16;
constexpr unsigned kT      = 1u << 19;
constexpr int      kHidden = 64;
constexpr int      kInDim  = 32;
constexpr int      kOutDim = 16;

struct LevelParams {
    float    scale[kLevels];
    unsigned res[kLevels];
    unsigned dense[kLevels];
};

typedef __attribute__((ext_vector_type(8))) short bf16x8;
typedef __attribute__((ext_vector_type(4))) float f32x4;
typedef __attribute__((ext_vector_type(2))) unsigned uint2v;
typedef __attribute__((ext_vector_type(4))) unsigned uint4v;

// ---- manual bf16 helpers ----
__device__ inline float bf2f(unsigned short b) {
    unsigned u = ((unsigned)b) << 16;
    return __builtin_bit_cast(float, u);
}
__device__ inline unsigned short f2bf(float f) {
    unsigned u = __builtin_bit_cast(unsigned, f);
    unsigned r = (u + 0x7fffu + ((u >> 16) & 1u)) >> 16;   // RTN-even
    return (unsigned short)r;
}
__device__ inline unsigned pack2bf(float a, float b) {
    return (unsigned)f2bf(a) | ((unsigned)f2bf(b) << 16);
}

// ---- kernel T: f32 table -> packed bf16 table in ws ----
__global__ __launch_bounds__(256) void convert_table(
        const float* __restrict__ t, unsigned* __restrict__ o, int n4)
{
    int i = blockIdx.x * blockDim.x + threadIdx.x;
    if (i >= n4) return;
    float4 v = ((const float4*)t)[i];
    ((uint2*)o)[i] = make_uint2(pack2bf(v.x, v.y), pack2bf(v.z, v.w));
}

// ---- R8: block-granular fused encode + MFMA MLP.
// History:
//  R5: cache tier irrelevant for gathers when level-major (pin: FETCH -2x, time -3%)
//  R6: gather pipe saturates ~16 waves/CU; MLP-widening null
//  R7: NAIVE fusion (lane owns 4 levels) => every wave hits all 16 tables,
//      L2 working set 32MB >> 4MB => FETCH 108MB -> 2.19GB, 626us. Locality
//      is the asset; fusion layout must preserve level-major gathers.
// This version: block owns 256 points. Phase 1: thread owns 1 point,
// loops levels 0..15 sequentially (block-uniform level => whole XCD on
// one 2MB L2-resident table at a time), writes packed enc to LDS
// [256][stride 20] via b128 every 4 levels (bank-balanced). Phase 2:
// 4 waves run the verified MFMA MLP on 4 local tiles each; A-fragment
// is one ds_read_b128/lane (bank-balanced, 16B aligned). Kills the
// 128MB enc roundtrip AND the 140us mlp tail; MLP hides in other
// blocks' gather shadow (4 blocks/CU).
// Keep: NO nt on table gathers (R4: defeats L2, 2x regression);
// pack2bf rounding identical to the verified split path.
__global__ __launch_bounds__(256, 4) void fused_block(
        const float* __restrict__ x,
        const unsigned* __restrict__ tblAll,   // [16][kT] packed bf16x2
        const float* __restrict__ W0,
        const float* __restrict__ b0,
        const float* __restrict__ W1,
        const float* __restrict__ b1,
        float* __restrict__ out, int N, int nChunks, LevelParams lp)
{
    constexpr int kEncStride = 20;             // 16 levels + 4 pad (units: u32)
    constexpr int kHStride = 72;
    __shared__ unsigned enc_lds[256 * kEncStride];   // 20 KB
    __shared__ short lds_h[4][16 * kHStride];        // 9 KB

    const int tid  = threadIdx.x;
    const int wave = tid >> 6;
    const int lane = tid & 63;
    const int quad = lane >> 4;
    const int l16  = lane & 15;

    union Frag { bf16x8 v; short s[8]; unsigned u[4]; };

    // ---- weight fragments (identical to verified mlp_mfma) ----
    Frag w0f[4];
    #pragma unroll
    for (int hb = 0; hb < 4; ++hb) {
        #pragma unroll
        for (int j = 0; j < 8; ++j) {
            const int k = quad * 8 + j;
            const int n = hb * 16 + l16;
            w0f[hb].s[j] = (short)f2bf(W0[n * kInDim + k]);
        }
    }
    Frag w1f[2];
    #pragma unroll
    for (int kb = 0; kb < 2; ++kb) {
        #pragma unroll
        for (int j = 0; j < 8; ++j) {
            const int k = kb * 32 + quad * 8 + j;
            const int n = l16;
            w1f[kb].s[j] = (short)f2bf(W1[n * kHidden + k]);
        }
    }
    float b0v[4];
    #pragma unroll
    for (int hb = 0; hb < 4; ++hb) b0v[hb] = b0[hb * 16 + l16];
    const float b1v = b1[l16];

    short* hrow = lds_h[wave];

    for (int chunk = blockIdx.x; chunk < nChunks; chunk += gridDim.x) {
        const int base = chunk * 256;

        // ---- phase 1: encode my point, levels 0..15 (level-major) ----
        int p = base + tid;
        if (p >= N) p = N - 1;
        const float x0 = fminf(fmaxf((x[3 * p + 0] + 1.0f) * 0.5f, 0.0f), 1.0f);
        const float y0 = fminf(fmaxf((x[3 * p + 1] + 1.0f) * 0.5f, 0.0f), 1.0f);
        const float z0 = fminf(fmaxf((x[3 * p + 2] + 1.0f) * 0.5f, 0.0f), 1.0f);

        #pragma unroll
        for (int lb = 0; lb < 4; ++lb) {
            unsigned encq[4];
            #pragma unroll
            for (int j = 0; j < 4; ++j) {
                const int l = lb * 4 + j;                 // compile-time level
                const float    scale = lp.scale[l];
                const unsigned res   = lp.res[l];
                const bool     dense = (lp.dense[l] != 0);
                const unsigned* tbl  = tblAll + (size_t)l * kT;

                const float posx = x0 * scale + 0.5f;
                const float posy = y0 * scale + 0.5f;
                const float posz = z0 * scale + 0.5f;
                const float fgx = floorf(posx), fgy = floorf(posy), fgz = floorf(posz);
                const float fx = posx - fgx, fy = posy - fgy, fz = posz - fgz;
                const float gx = 1.0f - fx,  gy = 1.0f - fy,  gz = 1.0f - fz;
                const unsigned ix = (unsigned)fgx, iy = (unsigned)fgy, iz = (unsigned)fgz;

                unsigned v0[4], v1[4];
                float    wyz[4];
                #pragma unroll
                for (int c2 = 0; c2 < 4; ++c2) {
                    const unsigned cy = iy + (c2 & 1);
                    const unsigned cz = iz + (c2 >> 1);
                    wyz[c2] = ((c2 & 1) ? fy : gy) * ((c2 >> 1) ? fz : gz);

                    if (dense) {
                        const unsigned bse = cy * res + cz * res * res;
                        const unsigned idx0 = (ix + bse) & (kT - 1u);
                        if ((idx0 & 1u) == 0u) {
                            const uint2v pr = *(const uint2v*)(tbl + idx0);
                            v0[c2] = pr.x; v1[c2] = pr.y;
                        } else {
                            v0[c2] = tbl[idx0];
                            v1[c2] = tbl[idx0 + 1u];
                        }
                    } else {
                        const unsigned bse = (cy * 2654435761u) ^ (cz * 805459861u);
                        const unsigned idx0 = (ix ^ bse) & (kT - 1u);
                        if ((ix & 1u) == 0u) {
                            const unsigned b = idx0 & ~1u;
                            const uint2v pr = *(const uint2v*)(tbl + b);
                            const bool sw = (idx0 & 1u) != 0u;
                            v0[c2] = sw ? pr.y : pr.x;
                            v1[c2] = sw ? pr.x : pr.y;
                        } else {
                            const unsigned idx1 = ((ix + 1u) ^ bse) & (kT - 1u);
                            v0[c2] = tbl[idx0];
                            v1[c2] = tbl[idx1];
                        }
                    }
                }

                float a0 = 0.0f, a1 = 0.0f;
                #pragma unroll
                for (int c2 = 0; c2 < 4; ++c2) {
                    const float w0w = gx * wyz[c2];
                    const float w1w = fx * wyz[c2];
                    a0 = fmaf(bf2f((unsigned short)(v0[c2] & 0xffffu)), w0w, a0);
                    a1 = fmaf(bf2f((unsigned short)(v0[c2] >> 16)),     w0w, a1);
                    a0 = fmaf(bf2f((unsigned short)(v1[c2] & 0xffffu)), w1w, a0);
                    a1 = fmaf(bf2f((unsigned short)(v1[c2] >> 16)),     w1w, a1);
                }
                encq[j] = pack2bf(a0, a1);
            }
            // bank-balanced 16B write: addr = tid*80 + lb*16 bytes
            *(uint4v*)&enc_lds[tid * kEncStride + lb * 4] =
                uint4v{encq[0], encq[1], encq[2], encq[3]};
        }

        __syncthreads();

        // ---- phase 2: MFMA MLP, 4 local tiles per wave ----
        #pragma unroll
        for (int tt = 0; tt < 4; ++tt) {
            const int tileLocal = wave + tt * 4;
            const int Plocal = tileLocal * 16;

            Frag af;
            af = *(const Frag*)&enc_lds[(Plocal + l16) * kEncStride + quad * 4];

            f32x4 acc[4];
            #pragma unroll
            for (int hb = 0; hb < 4; ++hb) {
                acc[hb] = f32x4{b0v[hb], b0v[hb], b0v[hb], b0v[hb]};
                acc[hb] = __builtin_amdgcn_mfma_f32_16x16x32_bf16(
                              af.v, w0f[hb].v, acc[hb], 0, 0, 0);
            }

            #pragma unroll
            for (int hb = 0; hb < 4; ++hb) {
                #pragma unroll
                for (int r = 0; r < 4; ++r) {
                    const float a = acc[hb][r];
                    const float z = 100.0f * a;
                    const float h = (z > 20.0f) ? a
                                  : (__logf(1.0f + __expf(z)) * 0.01f);
                    const int row = quad * 4 + r;
                    const int col = hb * 16 + l16;
                    hrow[row * kHStride + col] = (short)f2bf(h);
                }
            }
            bf16x8 h0 = *(const bf16x8*)&hrow[l16 * kHStride + quad * 8];
            bf16x8 h1 = *(const bf16x8*)&hrow[l16 * kHStride + 32 + quad * 8];

            f32x4 acc2 = f32x4{b1v, b1v, b1v, b1v};
            acc2 = __builtin_amdgcn_mfma_f32_16x16x32_bf16(h0, w1f[0].v, acc2, 0, 0, 0);
            acc2 = __builtin_amdgcn_mfma_f32_16x16x32_bf16(h1, w1f[1].v, acc2, 0, 0, 0);

            #pragma unroll
            for (int r = 0; r < 4; ++r) {
                const int pp = base + Plocal + quad * 4 + r;
                if (pp < N) {
                    if (l16 == 0) out[pp] = acc2[r];
                    else out[(size_t)N + (size_t)pp * 15u + (l16 - 1)] = acc2[r];
                }
            }
        }

        __syncthreads();   // protect enc_lds before next chunk's writes
    }
}

// ---- fallback: fused scalar kernel (used only if ws too small) ----
__global__ __launch_bounds__(256) void sdf_fused(
        const float* __restrict__ x, const float* __restrict__ table,
        const float* __restrict__ W0, const float* __restrict__ b0,
        const float* __restrict__ W1, const float* __restrict__ b1,
        float* __restrict__ out, int N, LevelParams lp)
{
    const int gid = blockIdx.x * blockDim.x + threadIdx.x;
    if (gid >= N) return;
    const float x0 = fminf(fmaxf((x[3 * gid + 0] + 1.0f) * 0.5f, 0.0f), 1.0f);
    const float y0 = fminf(fmaxf((x[3 * gid + 1] + 1.0f) * 0.5f, 0.0f), 1.0f);
    const float z0 = fminf(fmaxf((x[3 * gid + 2] + 1.0f) * 0.5f, 0.0f), 1.0f);
    float enc[kInDim];
    #pragma unroll
    for (int l = 0; l < kLevels; ++l) {
        const float scale = lp.scale[l];
        const unsigned res = lp.res[l];
        const bool dense = (lp.dense[l] != 0);
        const float posx = x0 * scale + 0.5f, posy = y0 * scale + 0.5f, posz = z0 * scale + 0.5f;
        const float fgx = floorf(posx), fgy = floorf(posy), fgz = floorf(posz);
        const float fx = posx - fgx, fy = posy - fgy, fz = posz - fgz;
        const float gx = 1.0f - fx, gy = 1.0f - fy, gz = 1.0f - fz;
        const unsigned ix = (unsigned)fgx, iy = (unsigned)fgy, iz = (unsigned)fgz;
        const float* tbl = table + (size_t)l * kT * 2u;
        float a0 = 0.0f, a1 = 0.0f;
        #pragma unroll
        for (int c = 0; c < 8; ++c) {
            const unsigned cx = ix + (c & 1), cy = iy + ((c >> 1) & 1), cz = iz + ((c >> 2) & 1);
            unsigned idx = dense ? (cx + cy * res + cz * res * res)
                                 : (cx ^ (cy * 2654435761u) ^ (cz * 805459861u));
            idx &= (kT - 1u);
            const float2 tv = *(const float2*)(tbl + 2u * idx);
            const float w = ((c & 1) ? fx : gx) * (((c >> 1) & 1) ? fy : gy) * (((c >> 2) & 1) ? fz : gz);
            a0 = fmaf(tv.x, w, a0); a1 = fmaf(tv.y, w, a1);
        }
        enc[2 * l] = a0; enc[2 * l + 1] = a1;
    }
    float acc[kOutDim];
    #pragma unroll
    for (int k = 0; k < kOutDim; ++k) acc[k] = b1[k];
    #pragma unroll 2
    for (int j = 0; j < kHidden; ++j) {
        float a = b0[j];
        #pragma unroll
        for (int i = 0; i < kInDim; ++i) a = fmaf(enc[i], W0[j * kInDim + i], a);
        const float z = 100.0f * a;
        const float h = (z > 20.0f) ? a : (__logf(1.0f + __expf(z)) * 0.01f);
        #pragma unroll
        for (int k = 0; k < kOutDim; ++k) acc[k] = fmaf(h, W1[k * kHidden + j], acc[k]);
    }
    out[gid] = acc[0];
    #pragma unroll
    for (int k = 0; k < 15; ++k) out[(size_t)N + (size_t)gid * 15u + k] = acc[k + 1];
}

extern "C" void kernel_launch(void* const* d_in, const int* in_sizes, int n_in,
                              void* d_out, int out_size, void* d_ws, size_t ws_size,
                              hipStream_t stream) {
    const float* x     = (const float*)d_in[0];
    const float* table = (const float*)d_in[1];
    const float* W0    = (const float*)d_in[2];
    const float* b0    = (const float*)d_in[3];
    const float* W1    = (const float*)d_in[4];
    const float* b1    = (const float*)d_in[5];
    float* out = (float*)d_out;
    const int N = in_sizes[0] / 3;

    LevelParams lp;
    const double s = exp2(7.0 / 15.0);
    for (int l = 0; l < kLevels; ++l) {
        const double sc = 16.0 * pow(s, (double)l) - 1.0;
        lp.scale[l] = (float)sc;
        const unsigned res = (unsigned)ceil(sc) + 1u;
        lp.res[l] = res;
        lp.dense[l] =
            ((unsigned long long)res * res * res <= (unsigned long long)kT) ? 1u : 0u;
    }

    const size_t tbl_bytes = (size_t)kLevels * kT * 4u;              // 32 MB packed bf16x2

    if (ws_size >= tbl_bytes) {
        unsigned* tbl_bf = (unsigned*)d_ws;

        const int n4 = (int)(kLevels * kT * 2u / 4u);
        hipLaunchKernelGGL(convert_table, dim3((n4 + 255) / 256), dim3(256), 0, stream,
                           table, tbl_bf, n4);

        const int nChunks = (N + 255) / 256;
        hipLaunchKernelGGL(fused_block, dim3(1024), dim3(256), 0, stream,
                           x, tbl_bf, W0, b0, W1, b1, out, N, nChunks, lp);
    } else {
        hipLaunchKernelGGL(sdf_fused, dim3((N + 255) / 256), dim3(256), 0, stream,
                           x, table, W0, b0, W1, b1, out, N, lp);
    }
}

// Round 6
// 495.173 us; speedup vs baseline: 1.4797x; 1.2534x over previous
//
#include <hip/hip_runtime.h>
#include <math.h>

constexpr int      kLevels = 16;
constexpr unsigned kT      = 1u << 19;
constexpr int      kHidden = 64;
constexpr int      kInDim  = 32;
constexpr int      kOutDim = 16;

struct LevelParams {
    float    scale[kLevels];
    unsigned res[kLevels];
    unsigned dense[kLevels];
};

typedef __attribute__((ext_vector_type(8))) short bf16x8;
typedef __attribute__((ext_vector_type(4))) float f32x4;

// ---- manual bf16 helpers ----
__device__ inline float bf2f(unsigned short b) {
    unsigned u = ((unsigned)b) << 16;
    return __builtin_bit_cast(float, u);
}
__device__ inline unsigned short f2bf(float f) {
    unsigned u = __builtin_bit_cast(unsigned, f);
    unsigned r = (u + 0x7fffu + ((u >> 16) & 1u)) >> 16;   // RTN-even
    return (unsigned short)r;
}
__device__ inline unsigned pack2bf(float a, float b) {
    return (unsigned)f2bf(a) | ((unsigned)f2bf(b) << 16);
}

// ---- kernel A: level-major encode, f32 table direct.
// History:
//  R4: nt on gathers defeats L2 => 2x regression. NEVER nt gathers.
//  R5: XCD-pinned levels: FETCH -2x, time -3% => cache tier irrelevant
//      for gather throughput; keep mapping (free, small win).
//  R6: 4pt/thread phase-split: occupancy 88->53% at same 271us =>
//      gather pipe saturates ~16 waves/CU; ~0.4 unique-lines/cyc/CU is
//      the empirical floor. Keep structure (tiny win over 2pt).
//  R7/R8: fusion (lane-level or block-level) destroys level-major
//      locality => FETCH 1.6-2.2GB, 510-626us. Level-major GRID is
//      mandatory: a block must live its whole life on one level.
//  R9 (this round): gather f32 pairs directly from the input table
//      (unique-line count identical; R5 proved bytes don't matter) =>
//      convert_table kernel deleted (-32us). enc stores now cacheable
//      (nt dropped) so mlp can read the tail of enc from L2.
__global__ __launch_bounds__(256) void encode_level(
        const float* __restrict__ x,
        const float* __restrict__ table,       // [16][kT] float2 entries
        unsigned* __restrict__ enc,            // [16][N]  packed bf16x2
        int N, int nxb, LevelParams lp)
{
    const int bid = blockIdx.x;
    const int tid = threadIdx.x;

    int l, xb;
    const int pinnedBlocks = 8 * nxb;
    if (bid < pinnedBlocks) {
        l  = 8 + (bid & 7);
        xb = bid >> 3;
    } else {
        const int r = bid - pinnedBlocks;
        l  = r / nxb;
        xb = r - l * nxb;
    }

    const float    scale = lp.scale[l];
    const unsigned res   = lp.res[l];
    const bool     dense = (lp.dense[l] != 0);   // wave-uniform
    const float2*  tbl   = (const float2*)table + (size_t)l * kT;

    const int pBase = xb * 1024 + tid;

    // ---- phase 1: x loads for 4 points ----
    float xs[4], ys[4], zs[4];
    #pragma unroll
    for (int q = 0; q < 4; ++q) {
        int p = pBase + q * 256;
        if (p >= N) p = N - 1;
        xs[q] = x[3 * p + 0];
        ys[q] = x[3 * p + 1];
        zs[q] = x[3 * p + 2];
    }

    // ---- phase 2: addresses + issue ALL gathers (held in regs) ----
    float2 v0[4][4], v1[4][4];
    float  wyz[4][4], wgx[4], wfx[4];

    #pragma unroll
    for (int q = 0; q < 4; ++q) {
        const float x0 = fminf(fmaxf((xs[q] + 1.0f) * 0.5f, 0.0f), 1.0f);
        const float y0 = fminf(fmaxf((ys[q] + 1.0f) * 0.5f, 0.0f), 1.0f);
        const float z0 = fminf(fmaxf((zs[q] + 1.0f) * 0.5f, 0.0f), 1.0f);

        const float posx = x0 * scale + 0.5f;
        const float posy = y0 * scale + 0.5f;
        const float posz = z0 * scale + 0.5f;
        const float fgx = floorf(posx), fgy = floorf(posy), fgz = floorf(posz);
        const float fx = posx - fgx, fy = posy - fgy, fz = posz - fgz;
        const float gy = 1.0f - fy,  gz = 1.0f - fz;
        const unsigned ix = (unsigned)fgx, iy = (unsigned)fgy, iz = (unsigned)fgz;

        wgx[q] = 1.0f - fx;
        wfx[q] = fx;

        #pragma unroll
        for (int c2 = 0; c2 < 4; ++c2) {
            const unsigned cy = iy + (c2 & 1);
            const unsigned cz = iz + (c2 >> 1);
            wyz[q][c2] = ((c2 & 1) ? fy : gy) * ((c2 >> 1) ? fz : gz);

            if (dense) {
                const unsigned base = cy * res + cz * res * res;
                const unsigned idx0 = (ix + base) & (kT - 1u);
                if ((idx0 & 1u) == 0u) {
                    const float4 pr = *(const float4*)(tbl + idx0);
                    v0[q][c2] = make_float2(pr.x, pr.y);
                    v1[q][c2] = make_float2(pr.z, pr.w);
                } else {
                    v0[q][c2] = tbl[idx0];
                    v1[q][c2] = tbl[idx0 + 1u];
                }
            } else {
                const unsigned base = (cy * 2654435761u) ^ (cz * 805459861u);
                const unsigned idx0 = (ix ^ base) & (kT - 1u);
                if ((ix & 1u) == 0u) {
                    // ix even -> idx1 = idx0 ^ 1: aligned pair covers both
                    const unsigned b = idx0 & ~1u;
                    const float4 pr = *(const float4*)(tbl + b);
                    const bool sw = (idx0 & 1u) != 0u;
                    v0[q][c2] = sw ? make_float2(pr.z, pr.w) : make_float2(pr.x, pr.y);
                    v1[q][c2] = sw ? make_float2(pr.x, pr.y) : make_float2(pr.z, pr.w);
                } else {
                    const unsigned idx1 = ((ix + 1u) ^ base) & (kT - 1u);
                    v0[q][c2] = tbl[idx0];
                    v1[q][c2] = tbl[idx1];
                }
            }
        }
    }

    // ---- phase 3: consume + store (cacheable: mlp reads enc next) ----
    #pragma unroll
    for (int q = 0; q < 4; ++q) {
        float a0 = 0.0f, a1 = 0.0f;
        #pragma unroll
        for (int c2 = 0; c2 < 4; ++c2) {
            const float w0 = wgx[q] * wyz[q][c2];
            const float w1 = wfx[q] * wyz[q][c2];
            a0 = fmaf(v0[q][c2].x, w0, a0);
            a1 = fmaf(v0[q][c2].y, w0, a1);
            a0 = fmaf(v1[q][c2].x, w1, a0);
            a1 = fmaf(v1[q][c2].y, w1, a1);
        }
        const int p = pBase + q * 256;
        if (p < N)
            enc[(size_t)l * N + p] = pack2bf(a0, a1);
    }
}

// ---- kernel B: MFMA MLP over bf16 enc ----
// R6: software-pipelined enc prefetch. R9: out stores nontemporal
// (64MB never re-read; keep L2 for enc).
__global__ __launch_bounds__(256) void mlp_mfma(
        const unsigned* __restrict__ enc,      // [16][N] packed bf16x2
        const float* __restrict__ W0,
        const float* __restrict__ b0,
        const float* __restrict__ W1,
        const float* __restrict__ b1,
        float* __restrict__ out, int N, int nTiles)
{
    constexpr int kHStride = 72;
    __shared__ short lds_h[4][16 * kHStride];

    const int wave = threadIdx.x >> 6;
    const int lane = threadIdx.x & 63;
    const int quad = lane >> 4;
    const int l16  = lane & 15;

    union Frag { bf16x8 v; short s[8]; unsigned u[4]; };

    Frag w0f[4];
    #pragma unroll
    for (int hb = 0; hb < 4; ++hb) {
        #pragma unroll
        for (int j = 0; j < 8; ++j) {
            const int k = quad * 8 + j;
            const int n = hb * 16 + l16;
            w0f[hb].s[j] = (short)f2bf(W0[n * kInDim + k]);
        }
    }
    Frag w1f[2];
    #pragma unroll
    for (int kb = 0; kb < 2; ++kb) {
        #pragma unroll
        for (int j = 0; j < 8; ++j) {
            const int k = kb * 32 + quad * 8 + j;
            const int n = l16;
            w1f[kb].s[j] = (short)f2bf(W1[n * kHidden + k]);
        }
    }
    float b0v[4];
    #pragma unroll
    for (int hb = 0; hb < 4; ++hb) b0v[hb] = b0[hb * 16 + l16];
    const float b1v = b1[l16];

    short* hrow = lds_h[wave];
    const int waveGlobal = blockIdx.x * 4 + wave;
    const int nWaves     = gridDim.x * 4;

    auto loadFrag = [&](int t, Frag& f) {
        const int P = t * 16;
        int p = P + l16;
        if (p >= N) p = N - 1;
        #pragma unroll
        for (int j2 = 0; j2 < 4; ++j2)
            f.u[j2] = enc[(size_t)(quad * 4 + j2) * N + p];
    };

    int t = waveGlobal;
    if (t >= nTiles) return;

    Frag af;
    loadFrag(t, af);

    for (; t < nTiles; t += nWaves) {
        // prefetch next tile while computing this one
        const int tn = t + nWaves;
        Frag afn;
        if (tn < nTiles) loadFrag(tn, afn);

        const int P = t * 16;

        f32x4 acc[4];
        #pragma unroll
        for (int hb = 0; hb < 4; ++hb) {
            acc[hb] = f32x4{b0v[hb], b0v[hb], b0v[hb], b0v[hb]};
            acc[hb] = __builtin_amdgcn_mfma_f32_16x16x32_bf16(
                          af.v, w0f[hb].v, acc[hb], 0, 0, 0);
        }

        #pragma unroll
        for (int hb = 0; hb < 4; ++hb) {
            #pragma unroll
            for (int r = 0; r < 4; ++r) {
                const float a = acc[hb][r];
                const float z = 100.0f * a;
                const float h = (z > 20.0f) ? a
                              : (__logf(1.0f + __expf(z)) * 0.01f);
                const int row = quad * 4 + r;
                const int col = hb * 16 + l16;
                hrow[row * kHStride + col] = (short)f2bf(h);
            }
        }
        bf16x8 h0 = *(const bf16x8*)&hrow[l16 * kHStride + quad * 8];
        bf16x8 h1 = *(const bf16x8*)&hrow[l16 * kHStride + 32 + quad * 8];

        f32x4 acc2 = f32x4{b1v, b1v, b1v, b1v};
        acc2 = __builtin_amdgcn_mfma_f32_16x16x32_bf16(h0, w1f[0].v, acc2, 0, 0, 0);
        acc2 = __builtin_amdgcn_mfma_f32_16x16x32_bf16(h1, w1f[1].v, acc2, 0, 0, 0);

        #pragma unroll
        for (int r = 0; r < 4; ++r) {
            const int pp = P + quad * 4 + r;
            if (pp < N) {
                if (l16 == 0)
                    __builtin_nontemporal_store(acc2[r], &out[pp]);
                else
                    __builtin_nontemporal_store(acc2[r],
                        &out[(size_t)N + (size_t)pp * 15u + (l16 - 1)]);
            }
        }

        af = afn;
    }
}

// ---- fallback: fused scalar kernel (used only if ws too small) ----
__global__ __launch_bounds__(256) void sdf_fused(
        const float* __restrict__ x, const float* __restrict__ table,
        const float* __restrict__ W0, const float* __restrict__ b0,
        const float* __restrict__ W1, const float* __restrict__ b1,
        float* __restrict__ out, int N, LevelParams lp)
{
    const int gid = blockIdx.x * blockDim.x + threadIdx.x;
    if (gid >= N) return;
    const float x0 = fminf(fmaxf((x[3 * gid + 0] + 1.0f) * 0.5f, 0.0f), 1.0f);
    const float y0 = fminf(fmaxf((x[3 * gid + 1] + 1.0f) * 0.5f, 0.0f), 1.0f);
    const float z0 = fminf(fmaxf((x[3 * gid + 2] + 1.0f) * 0.5f, 0.0f), 1.0f);
    float enc[kInDim];
    #pragma unroll
    for (int l = 0; l < kLevels; ++l) {
        const float scale = lp.scale[l];
        const unsigned res = lp.res[l];
        const bool dense = (lp.dense[l] != 0);
        const float posx = x0 * scale + 0.5f, posy = y0 * scale + 0.5f, posz = z0 * scale + 0.5f;
        const float fgx = floorf(posx), fgy = floorf(posy), fgz = floorf(posz);
        const float fx = posx - fgx, fy = posy - fgy, fz = posz - fgz;
        const float gx = 1.0f - fx, gy = 1.0f - fy, gz = 1.0f - fz;
        const unsigned ix = (unsigned)fgx, iy = (unsigned)fgy, iz = (unsigned)fgz;
        const float* tbl = table + (size_t)l * kT * 2u;
        float a0 = 0.0f, a1 = 0.0f;
        #pragma unroll
        for (int c = 0; c < 8; ++c) {
            const unsigned cx = ix + (c & 1), cy = iy + ((c >> 1) & 1), cz = iz + ((c >> 2) & 1);
            unsigned idx = dense ? (cx + cy * res + cz * res * res)
                                 : (cx ^ (cy * 2654435761u) ^ (cz * 805459861u));
            idx &= (kT - 1u);
            const float2 tv = *(const float2*)(tbl + 2u * idx);
            const float w = ((c & 1) ? fx : gx) * (((c >> 1) & 1) ? fy : gy) * (((c >> 2) & 1) ? fz : gz);
            a0 = fmaf(tv.x, w, a0); a1 = fmaf(tv.y, w, a1);
        }
        enc[2 * l] = a0; enc[2 * l + 1] = a1;
    }
    float acc[kOutDim];
    #pragma unroll
    for (int k = 0; k < kOutDim; ++k) acc[k] = b1[k];
    #pragma unroll 2
    for (int j = 0; j < kHidden; ++j) {
        float a = b0[j];
        #pragma unroll
        for (int i = 0; i < kInDim; ++i) a = fmaf(enc[i], W0[j * kInDim + i], a);
        const float z = 100.0f * a;
        const float h = (z > 20.0f) ? a : (__logf(1.0f + __expf(z)) * 0.01f);
        #pragma unroll
        for (int k = 0; k < kOutDim; ++k) acc[k] = fmaf(h, W1[k * kHidden + j], acc[k]);
    }
    out[gid] = acc[0];
    #pragma unroll
    for (int k = 0; k < 15; ++k) out[(size_t)N + (size_t)gid * 15u + k] = acc[k + 1];
}

extern "C" void kernel_launch(void* const* d_in, const int* in_sizes, int n_in,
                              void* d_out, int out_size, void* d_ws, size_t ws_size,
                              hipStream_t stream) {
    const float* x     = (const float*)d_in[0];
    const float* table = (const float*)d_in[1];
    const float* W0    = (const float*)d_in[2];
    const float* b0    = (const float*)d_in[3];
    const float* W1    = (const float*)d_in[4];
    const float* b1    = (const float*)d_in[5];
    float* out = (float*)d_out;
    const int N = in_sizes[0] / 3;

    LevelParams lp;
    const double s = exp2(7.0 / 15.0);
    for (int l = 0; l < kLevels; ++l) {
        const double sc = 16.0 * pow(s, (double)l) - 1.0;
        lp.scale[l] = (float)sc;
        const unsigned res = (unsigned)ceil(sc) + 1u;
        lp.res[l] = res;
        lp.dense[l] =
            ((unsigned long long)res * res * res <= (unsigned long long)kT) ? 1u : 0u;
    }

    const size_t enc_bytes = (size_t)kLevels * (size_t)N * 4u;       // 64 MB packed bf16x2

    if (ws_size >= enc_bytes) {
        unsigned* enc = (unsigned*)d_ws;

        const int nxb = (N + 1023) / 1024;
        hipLaunchKernelGGL(encode_level, dim3(16 * nxb), dim3(256), 0, stream,
                           x, table, enc, N, nxb, lp);

        const int nTiles = (N + 15) / 16;
        hipLaunchKernelGGL(mlp_mfma, dim3(2048), dim3(256), 0, stream,
                           enc, W0, b0, W1, b1, out, N, nTiles);
    } else {
        hipLaunchKernelGGL(sdf_fused, dim3((N + 255) / 256), dim3(256), 0, stream,
                           x, table, W0, b0, W1, b1, out, N, lp);
    }
}

// Round 7
// 435.576 us; speedup vs baseline: 1.6821x; 1.1368x over previous
//
#include <hip/hip_runtime.h>
#include <math.h>

constexpr int      kLevels = 16;
constexpr unsigned kT      = 1u << 19;
constexpr int      kHidden = 64;
constexpr int      kInDim  = 32;
constexpr int      kOutDim = 16;

struct LevelParams {
    float    scale[kLevels];
    unsigned res[kLevels];
    unsigned dense[kLevels];
};

typedef __attribute__((ext_vector_type(8))) short bf16x8;
typedef __attribute__((ext_vector_type(4))) float f32x4;
typedef __attribute__((ext_vector_type(2))) unsigned uint2v;

// ---- manual bf16 helpers ----
__device__ inline float bf2f(unsigned short b) {
    unsigned u = ((unsigned)b) << 16;
    return __builtin_bit_cast(float, u);
}
__device__ inline unsigned short f2bf(float f) {
    unsigned u = __builtin_bit_cast(unsigned, f);
    unsigned r = (u + 0x7fffu + ((u >> 16) & 1u)) >> 16;   // RTN-even
    return (unsigned short)r;
}
__device__ inline unsigned pack2bf(float a, float b) {
    return (unsigned)f2bf(a) | ((unsigned)f2bf(b) << 16);
}

// ---- kernel T: f32 table -> packed bf16 table in ws ----
// R9 lesson: this conversion is NOT overhead — bf16 keeps hashed tables
// at 2MB (L2-resident under pinning) and halves gather payload. f32-direct
// gathers regressed encode 271->359us (FETCH 108->297MB).
__global__ __launch_bounds__(256) void convert_table(
        const float* __restrict__ t, unsigned* __restrict__ o, int n4)
{
    int i = blockIdx.x * blockDim.x + threadIdx.x;
    if (i >= n4) return;
    float4 v = ((const float4*)t)[i];
    ((uint2*)o)[i] = make_uint2(pack2bf(v.x, v.y), pack2bf(v.z, v.w));
}

// ---- kernel A: level-major encode (VERIFIED 271us floor config).
// History:
//  R4: nt on gathers defeats L2 => 2x regression. NEVER nt gathers.
//  R5: XCD-pinned levels 8..15: FETCH -2x; keep (free win).
//  R6: 4pt/thread: occupancy 88->53% at same 271us => gather pipe
//      saturates ~16 waves/CU; this is the empirical floor.
//  R7/R8: fusion destroys level-major locality => 1.6-2.2GB FETCH.
//      Level-major GRID mandatory (block lives on ONE level).
//  R9: f32-direct tables regressed (4MB table = whole L2). bf16 stays.
__global__ __launch_bounds__(256) void encode_level(
        const float* __restrict__ x,
        const unsigned* __restrict__ tblAll,   // [16][kT] packed bf16x2
        unsigned* __restrict__ enc,            // [16][N]  packed bf16x2
        int N, int nxb, LevelParams lp)
{
    const int bid = blockIdx.x;
    const int tid = threadIdx.x;

    int l, xb;
    const int pinnedBlocks = 8 * nxb;
    if (bid < pinnedBlocks) {
        l  = 8 + (bid & 7);
        xb = bid >> 3;
    } else {
        const int r = bid - pinnedBlocks;
        l  = r / nxb;
        xb = r - l * nxb;
    }

    const float    scale = lp.scale[l];
    const unsigned res   = lp.res[l];
    const bool     dense = (lp.dense[l] != 0);   // wave-uniform
    const unsigned* tbl  = tblAll + (size_t)l * kT;

    const int pBase = xb * 1024 + tid;

    // ---- phase 1: x loads for 4 points ----
    float xs[4], ys[4], zs[4];
    #pragma unroll
    for (int q = 0; q < 4; ++q) {
        int p = pBase + q * 256;
        if (p >= N) p = N - 1;
        xs[q] = x[3 * p + 0];
        ys[q] = x[3 * p + 1];
        zs[q] = x[3 * p + 2];
    }

    // ---- phase 2: addresses + issue ALL gathers (held in regs) ----
    unsigned v0[4][4], v1[4][4];
    float    wyz[4][4], wgx[4], wfx[4];

    #pragma unroll
    for (int q = 0; q < 4; ++q) {
        const float x0 = fminf(fmaxf((xs[q] + 1.0f) * 0.5f, 0.0f), 1.0f);
        const float y0 = fminf(fmaxf((ys[q] + 1.0f) * 0.5f, 0.0f), 1.0f);
        const float z0 = fminf(fmaxf((zs[q] + 1.0f) * 0.5f, 0.0f), 1.0f);

        const float posx = x0 * scale + 0.5f;
        const float posy = y0 * scale + 0.5f;
        const float posz = z0 * scale + 0.5f;
        const float fgx = floorf(posx), fgy = floorf(posy), fgz = floorf(posz);
        const float fx = posx - fgx, fy = posy - fgy, fz = posz - fgz;
        const float gy = 1.0f - fy,  gz = 1.0f - fz;
        const unsigned ix = (unsigned)fgx, iy = (unsigned)fgy, iz = (unsigned)fgz;

        wgx[q] = 1.0f - fx;
        wfx[q] = fx;

        #pragma unroll
        for (int c2 = 0; c2 < 4; ++c2) {
            const unsigned cy = iy + (c2 & 1);
            const unsigned cz = iz + (c2 >> 1);
            wyz[q][c2] = ((c2 & 1) ? fy : gy) * ((c2 >> 1) ? fz : gz);

            if (dense) {
                const unsigned base = cy * res + cz * res * res;
                const unsigned idx0 = (ix + base) & (kT - 1u);
                if ((idx0 & 1u) == 0u) {
                    const uint2v pr = *(const uint2v*)(tbl + idx0);
                    v0[q][c2] = pr.x; v1[q][c2] = pr.y;
                } else {
                    v0[q][c2] = tbl[idx0];
                    v1[q][c2] = tbl[idx0 + 1u];
                }
            } else {
                const unsigned base = (cy * 2654435761u) ^ (cz * 805459861u);
                const unsigned idx0 = (ix ^ base) & (kT - 1u);
                if ((ix & 1u) == 0u) {
                    // ix even -> idx1 = idx0 ^ 1: aligned pair covers both
                    const unsigned b = idx0 & ~1u;
                    const uint2v pr = *(const uint2v*)(tbl + b);
                    const bool sw = (idx0 & 1u) != 0u;
                    v0[q][c2] = sw ? pr.y : pr.x;
                    v1[q][c2] = sw ? pr.x : pr.y;
                } else {
                    const unsigned idx1 = ((ix + 1u) ^ base) & (kT - 1u);
                    v0[q][c2] = tbl[idx0];
                    v1[q][c2] = tbl[idx1];
                }
            }
        }
    }

    // ---- phase 3: consume + store ----
    #pragma unroll
    for (int q = 0; q < 4; ++q) {
        float a0 = 0.0f, a1 = 0.0f;
        #pragma unroll
        for (int c2 = 0; c2 < 4; ++c2) {
            const float w0 = wgx[q] * wyz[q][c2];
            const float w1 = wfx[q] * wyz[q][c2];
            a0 = fmaf(bf2f((unsigned short)(v0[q][c2] & 0xffffu)), w0, a0);
            a1 = fmaf(bf2f((unsigned short)(v0[q][c2] >> 16)),     w0, a1);
            a0 = fmaf(bf2f((unsigned short)(v1[q][c2] & 0xffffu)), w1, a0);
            a1 = fmaf(bf2f((unsigned short)(v1[q][c2] >> 16)),     w1, a1);
        }
        const int p = pBase + q * 256;
        if (p < N)
            __builtin_nontemporal_store(pack2bf(a0, a1), &enc[(size_t)l * N + p]);
    }
}

// ---- kernel B: MFMA MLP over bf16 enc ----
// R6: software-pipelined enc prefetch.
// R10 (this round): LDS-staged COALESCED output epilogue. Old path
// scattered geo as 60B ragged segments (15-float rows per point) ->
// mlp ran at ~1 TB/s on 128MB. New: stage 16x16 tile outputs in
// per-wave LDS (1KB), re-emit geo as 4x 64-lane contiguous dword
// bursts (960B/tile contiguous at out+N+P*15) + one 64B sdf burst.
// Stores nontemporal (out never re-read).
__global__ __launch_bounds__(256) void mlp_mfma(
        const unsigned* __restrict__ enc,      // [16][N] packed bf16x2
        const float* __restrict__ W0,
        const float* __restrict__ b0,
        const float* __restrict__ W1,
        const float* __restrict__ b1,
        float* __restrict__ out, int N, int nTiles)
{
    constexpr int kHStride = 72;
    __shared__ short lds_h[4][16 * kHStride];
    __shared__ float lds_o[4][16 * 16];

    const int wave = threadIdx.x >> 6;
    const int lane = threadIdx.x & 63;
    const int quad = lane >> 4;
    const int l16  = lane & 15;

    union Frag { bf16x8 v; short s[8]; unsigned u[4]; };

    Frag w0f[4];
    #pragma unroll
    for (int hb = 0; hb < 4; ++hb) {
        #pragma unroll
        for (int j = 0; j < 8; ++j) {
            const int k = quad * 8 + j;
            const int n = hb * 16 + l16;
            w0f[hb].s[j] = (short)f2bf(W0[n * kInDim + k]);
        }
    }
    Frag w1f[2];
    #pragma unroll
    for (int kb = 0; kb < 2; ++kb) {
        #pragma unroll
        for (int j = 0; j < 8; ++j) {
            const int k = kb * 32 + quad * 8 + j;
            const int n = l16;
            w1f[kb].s[j] = (short)f2bf(W1[n * kHidden + k]);
        }
    }
    float b0v[4];
    #pragma unroll
    for (int hb = 0; hb < 4; ++hb) b0v[hb] = b0[hb * 16 + l16];
    const float b1v = b1[l16];

    short* hrow = lds_h[wave];
    float* orow = lds_o[wave];
    const int waveGlobal = blockIdx.x * 4 + wave;
    const int nWaves     = gridDim.x * 4;

    auto loadFrag = [&](int t, Frag& f) {
        const int P = t * 16;
        int p = P + l16;
        if (p >= N) p = N - 1;
        #pragma unroll
        for (int j2 = 0; j2 < 4; ++j2)
            f.u[j2] = enc[(size_t)(quad * 4 + j2) * N + p];
    };

    int t = waveGlobal;
    if (t >= nTiles) return;

    Frag af;
    loadFrag(t, af);

    for (; t < nTiles; t += nWaves) {
        // prefetch next tile while computing this one
        const int tn = t + nWaves;
        Frag afn;
        if (tn < nTiles) loadFrag(tn, afn);

        const int P = t * 16;

        f32x4 acc[4];
        #pragma unroll
        for (int hb = 0; hb < 4; ++hb) {
            acc[hb] = f32x4{b0v[hb], b0v[hb], b0v[hb], b0v[hb]};
            acc[hb] = __builtin_amdgcn_mfma_f32_16x16x32_bf16(
                          af.v, w0f[hb].v, acc[hb], 0, 0, 0);
        }

        #pragma unroll
        for (int hb = 0; hb < 4; ++hb) {
            #pragma unroll
            for (int r = 0; r < 4; ++r) {
                const float a = acc[hb][r];
                const float z = 100.0f * a;
                const float h = (z > 20.0f) ? a
                              : (__logf(1.0f + __expf(z)) * 0.01f);
                const int row = quad * 4 + r;
                const int col = hb * 16 + l16;
                hrow[row * kHStride + col] = (short)f2bf(h);
            }
        }
        bf16x8 h0 = *(const bf16x8*)&hrow[l16 * kHStride + quad * 8];
        bf16x8 h1 = *(const bf16x8*)&hrow[l16 * kHStride + 32 + quad * 8];

        f32x4 acc2 = f32x4{b1v, b1v, b1v, b1v};
        acc2 = __builtin_amdgcn_mfma_f32_16x16x32_bf16(h0, w1f[0].v, acc2, 0, 0, 0);
        acc2 = __builtin_amdgcn_mfma_f32_16x16x32_bf16(h1, w1f[1].v, acc2, 0, 0, 0);

        // ---- R10 epilogue: stage -> coalesced nt bursts ----
        // orow[pt][od]: pt = quad*4+r (point within tile), od = l16.
        #pragma unroll
        for (int r = 0; r < 4; ++r)
            orow[(quad * 4 + r) * 16 + l16] = acc2[r];
        // same-wave LDS write->read (in-order DS pipe; same pattern as hrow)

        // geo block: 240 contiguous floats at out + N + P*15
        float* gbase = out + (size_t)N + (size_t)P * 15u;
        #pragma unroll
        for (int gp = 0; gp < 4; ++gp) {
            const int g = gp * 64 + lane;
            if (g < 240) {
                const int pt = g / 15;
                const int k  = g - pt * 15;
                if (P + pt < N)
                    __builtin_nontemporal_store(orow[pt * 16 + k + 1], &gbase[g]);
            }
        }
        // sdf: 16 contiguous floats at out + P
        if (lane < 16 && P + lane < N)
            __builtin_nontemporal_store(orow[lane * 16 + 0], &out[P + lane]);

        af = afn;
    }
}

// ---- fallback: fused scalar kernel (used only if ws too small) ----
__global__ __launch_bounds__(256) void sdf_fused(
        const float* __restrict__ x, const float* __restrict__ table,
        const float* __restrict__ W0, const float* __restrict__ b0,
        const float* __restrict__ W1, const float* __restrict__ b1,
        float* __restrict__ out, int N, LevelParams lp)
{
    const int gid = blockIdx.x * blockDim.x + threadIdx.x;
    if (gid >= N) return;
    const float x0 = fminf(fmaxf((x[3 * gid + 0] + 1.0f) * 0.5f, 0.0f), 1.0f);
    const float y0 = fminf(fmaxf((x[3 * gid + 1] + 1.0f) * 0.5f, 0.0f), 1.0f);
    const float z0 = fminf(fmaxf((x[3 * gid + 2] + 1.0f) * 0.5f, 0.0f), 1.0f);
    float enc[kInDim];
    #pragma unroll
    for (int l = 0; l < kLevels; ++l) {
        const float scale = lp.scale[l];
        const unsigned res = lp.res[l];
        const bool dense = (lp.dense[l] != 0);
        const float posx = x0 * scale + 0.5f, posy = y0 * scale + 0.5f, posz = z0 * scale + 0.5f;
        const float fgx = floorf(posx), fgy = floorf(posy), fgz = floorf(posz);
        const float fx = posx - fgx, fy = posy - fgy, fz = posz - fgz;
        const float gx = 1.0f - fx, gy = 1.0f - fy, gz = 1.0f - fz;
        const unsigned ix = (unsigned)fgx, iy = (unsigned)fgy, iz = (unsigned)fgz;
        const float* tbl = table + (size_t)l * kT * 2u;
        float a0 = 0.0f, a1 = 0.0f;
        #pragma unroll
        for (int c = 0; c < 8; ++c) {
            const unsigned cx = ix + (c & 1), cy = iy + ((c >> 1) & 1), cz = iz + ((c >> 2) & 1);
            unsigned idx = dense ? (cx + cy * res + cz * res * res)
                                 : (cx ^ (cy * 2654435761u) ^ (cz * 805459861u));
            idx &= (kT - 1u);
            const float2 tv = *(const float2*)(tbl + 2u * idx);
            const float w = ((c & 1) ? fx : gx) * (((c >> 1) & 1) ? fy : gy) * (((c >> 2) & 1) ? fz : gz);
            a0 = fmaf(tv.x, w, a0); a1 = fmaf(tv.y, w, a1);
        }
        enc[2 * l] = a0; enc[2 * l + 1] = a1;
    }
    float acc[kOutDim];
    #pragma unroll
    for (int k = 0; k < kOutDim; ++k) acc[k] = b1[k];
    #pragma unroll 2
    for (int j = 0; j < kHidden; ++j) {
        float a = b0[j];
        #pragma unroll
        for (int i = 0; i < kInDim; ++i) a = fmaf(enc[i], W0[j * kInDim + i], a);
        const float z = 100.0f * a;
        const float h = (z > 20.0f) ? a : (__logf(1.0f + __expf(z)) * 0.01f);
        #pragma unroll
        for (int k = 0; k < kOutDim; ++k) acc[k] = fmaf(h, W1[k * kHidden + j], acc[k]);
    }
    out[gid] = acc[0];
    #pragma unroll
    for (int k = 0; k < 15; ++k) out[(size_t)N + (size_t)gid * 15u + k] = acc[k + 1];
}

extern "C" void kernel_launch(void* const* d_in, const int* in_sizes, int n_in,
                              void* d_out, int out_size, void* d_ws, size_t ws_size,
                              hipStream_t stream) {
    const float* x     = (const float*)d_in[0];
    const float* table = (const float*)d_in[1];
    const float* W0    = (const float*)d_in[2];
    const float* b0    = (const float*)d_in[3];
    const float* W1    = (const float*)d_in[4];
    const float* b1    = (const float*)d_in[5];
    float* out = (float*)d_out;
    const int N = in_sizes[0] / 3;

    LevelParams lp;
    const double s = exp2(7.0 / 15.0);
    for (int l = 0; l < kLevels; ++l) {
        const double sc = 16.0 * pow(s, (double)l) - 1.0;
        lp.scale[l] = (float)sc;
        const unsigned res = (unsigned)ceil(sc) + 1u;
        lp.res[l] = res;
        lp.dense[l] =
            ((unsigned long long)res * res * res <= (unsigned long long)kT) ? 1u : 0u;
    }

    const size_t tbl_bytes = (size_t)kLevels * kT * 4u;              // 32 MB packed bf16x2
    const size_t enc_bytes = (size_t)kLevels * (size_t)N * 4u;       // 64 MB packed bf16x2

    if (ws_size >= tbl_bytes + enc_bytes) {
        unsigned* tbl_bf = (unsigned*)d_ws;
        unsigned* enc    = (unsigned*)((char*)d_ws + tbl_bytes);

        const int n4 = (int)(kLevels * kT * 2u / 4u);
        hipLaunchKernelGGL(convert_table, dim3((n4 + 255) / 256), dim3(256), 0, stream,
                           table, tbl_bf, n4);

        const int nxb = (N + 1023) / 1024;
        hipLaunchKernelGGL(encode_level, dim3(16 * nxb), dim3(256), 0, stream,
                           x, tbl_bf, enc, N, nxb, lp);

        const int nTiles = (N + 15) / 16;
        hipLaunchKernelGGL(mlp_mfma, dim3(2048), dim3(256), 0, stream,
                           enc, W0, b0, W1, b1, out, N, nTiles);
    } else {
        hipLaunchKernelGGL(sdf_fused, dim3((N + 255) / 256), dim3(256), 0, stream,
                           x, table, W0, b0, W1, b1, out, N, lp);
    }
}